// Round 3
// baseline (548.328 us; speedup 1.0000x reference)
//
#include <hip/hip_runtime.h>
#include <hip/hip_bf16.h>

#define H 1024
#define I_DIM 704
#define E 32
#define TOPK_GROUP 3
#define K_TOP 6
#define T_TOK 2048
#define CAP 768
#define IS_DIM 1408   // N_SHARED * I
#define NCHUNK 192    // (T_TOK*K_TOP)/64

typedef __attribute__((ext_vector_type(8))) short short8v;
typedef __attribute__((ext_vector_type(4))) float f32x4;

__device__ __forceinline__ unsigned short f2bfbits(float f) {
  unsigned u = __float_as_uint(f);
  unsigned r = (u + 0x7fffu + ((u >> 16) & 1u)) >> 16;  // RTNE
  return (unsigned short)r;
}
__device__ __forceinline__ float bf2f(unsigned short b) {
  return __uint_as_float(((unsigned)b) << 16);
}
__device__ __forceinline__ void gload_lds16(const short* g, short* l) {
  __builtin_amdgcn_global_load_lds(
      (const __attribute__((address_space(1))) unsigned int*)g,
      (__attribute__((address_space(3))) unsigned int*)l, 16, 0, 0);
}

// ---------------- cast x (fp32) -> bf16 bits ----------------
__global__ void cast_x_kernel(const float* __restrict__ x, short* __restrict__ xb) {
  size_t i = ((size_t)blockIdx.x * 256 + threadIdx.x) * 4;
  float4 v = *(const float4*)(x + i);
  short4 s;
  s.x = (short)f2bfbits(v.x); s.y = (short)f2bfbits(v.y);
  s.z = (short)f2bfbits(v.z); s.w = (short)f2bfbits(v.w);
  *(short4*)(xb + i) = s;
}

// ---------------- cast+transpose weights: in fp32 [K][N] -> out bf16 [N][K] ----------------
__global__ __launch_bounds__(256) void tw_kernel(const float* __restrict__ in,
                                                 short* __restrict__ out,
                                                 int K, int N) {
  __shared__ float tile[64][65];
  long long eoff = (long long)blockIdx.z * (long long)K * N;
  const float* ip = in + eoff;
  short* op = out + eoff;
  int n0 = blockIdx.x * 64, k0 = blockIdx.y * 64;
  int t = threadIdx.x;
  int tr = t >> 4;          // 0..15
  int tc = (t & 15) * 4;    // 0..60
  #pragma unroll
  for (int i = 0; i < 4; ++i) {
    float4 v = *(const float4*)(ip + (size_t)(k0 + tr + i * 16) * N + n0 + tc);
    tile[tr + i * 16][tc + 0] = v.x;
    tile[tr + i * 16][tc + 1] = v.y;
    tile[tr + i * 16][tc + 2] = v.z;
    tile[tr + i * 16][tc + 3] = v.w;
  }
  __syncthreads();
  #pragma unroll
  for (int i = 0; i < 4; ++i) {
    int n = tr + i * 16;
    short4 s;
    s.x = (short)f2bfbits(tile[tc + 0][n]);
    s.y = (short)f2bfbits(tile[tc + 1][n]);
    s.z = (short)f2bfbits(tile[tc + 2][n]);
    s.w = (short)f2bfbits(tile[tc + 3][n]);
    *(short4*)(op + (size_t)(n0 + n) * K + k0 + tc) = s;
  }
}

// ---------------- gating: fp64 logits, lane-parallel softmax + group top-3 + top-6 ----------------
__global__ __launch_bounds__(64) void gating_kernel(const float* __restrict__ x,
                                                    const float* __restrict__ gw,
                                                    int* __restrict__ tidx,
                                                    float* __restrict__ tw) {
  int t = blockIdx.x;
  int lane = threadIdx.x;
  int e = lane & 31, half = lane >> 5;
  const float4* xr4 = (const float4*)(x + (size_t)t * H + half * 512);
  const float4* wr4 = (const float4*)(gw + (size_t)e * H + half * 512);
  double acc = 0.0;
  #pragma unroll 4
  for (int j = 0; j < 128; ++j) {
    float4 a = xr4[j], b = wr4[j];
    acc += (double)a.x * b.x + (double)a.y * b.y + (double)a.z * b.z + (double)a.w * b.w;
  }
  acc += __shfl_down(acc, 32);   // lanes 0..31 hold the 32 logits
  double lg = acc;
  double m = lg;
  #pragma unroll
  for (int off = 16; off >= 1; off >>= 1) {
    double o = __shfl_xor(m, off);
    if (o > m) m = o;
  }
  double p = exp(lg - m);
  double sum = p;
  #pragma unroll
  for (int off = 16; off >= 1; off >>= 1) sum += __shfl_xor(sum, off);
  p /= sum;
  double gmax = p;
  { double o = __shfl_xor(gmax, 1); if (o > gmax) gmax = o;
    o = __shfl_xor(gmax, 2); if (o > gmax) gmax = o; }
  bool gsel = false;
  double gv = gmax;
  #pragma unroll
  for (int it = 0; it < TOPK_GROUP; ++it) {
    double v = gv; int gi = e >> 2;
    #pragma unroll
    for (int off = 16; off >= 1; off >>= 1) {
      double ov = __shfl_xor(v, off);
      int oi = __shfl_xor(gi, off);
      if (ov > v || (ov == v && oi < gi)) { v = ov; gi = oi; }
    }
    if ((e >> 2) == gi) { gsel = true; gv = -1e300; }
  }
  double mp = gsel ? p : 0.0;
  #pragma unroll
  for (int it = 0; it < K_TOP; ++it) {
    double v = mp; int ei = e;
    #pragma unroll
    for (int off = 16; off >= 1; off >>= 1) {
      double ov = __shfl_xor(v, off);
      int oi = __shfl_xor(ei, off);
      if (ov > v || (ov == v && oi < ei)) { v = ov; ei = oi; }
    }
    if (lane == 0) { tidx[t * K_TOP + it] = ei; tw[t * K_TOP + it] = (float)v; }
    if (e == ei) mp = -2.0;
  }
}

// ---------------- dispatch phase 1: per-chunk histograms ----------------
__global__ __launch_bounds__(64) void hist_kernel(const int* __restrict__ tidx,
                                                  int* __restrict__ chunk_hist) {
  __shared__ int h[E];
  int c = blockIdx.x, lane = threadIdx.x;
  if (lane < E) h[lane] = 0;
  __syncthreads();
  int te = tidx[c * 64 + lane];
  atomicAdd(&h[te], 1);
  __syncthreads();
  if (lane < E) chunk_hist[c * E + lane] = h[lane];
}

// ---------------- dispatch phase 2: per-expert exclusive prefix over chunks ----------------
__global__ __launch_bounds__(1024) void scan_kernel(const int* __restrict__ chunk_hist,
                                                    int* __restrict__ chunk_base,
                                                    int* __restrict__ cnt) {
  __shared__ int h[NCHUNK * E];  // 24 KB
  int t = threadIdx.x;
  for (int i = t; i < NCHUNK * E; i += 1024) h[i] = chunk_hist[i];
  __syncthreads();
  if (t < E) {
    int run = 0;
    for (int c = 0; c < NCHUNK; ++c) {
      int v = h[c * E + t];
      h[c * E + t] = run;
      run += v;
    }
    cnt[t] = run < CAP ? run : CAP;
  }
  __syncthreads();
  for (int i = t; i < NCHUNK * E; i += 1024) chunk_base[i] = h[i];
}

// ---------------- dispatch phase 3: placement + inverse slot map ----------------
__global__ __launch_bounds__(64) void place_kernel(const int* __restrict__ tidx,
                                                   const int* __restrict__ chunk_base,
                                                   int* __restrict__ token_list,
                                                   int* __restrict__ sid) {
  int c = blockIdx.x, lane = threadIdx.x;
  int idx = c * 64 + lane;
  int te = tidx[idx];
  unsigned long long mymask = 0;
  #pragma unroll
  for (int e = 0; e < E; ++e) {
    unsigned long long bal = __ballot(te == e);
    if (te == e) mymask = bal;
  }
  int rank = __popcll(mymask & ((1ull << lane) - 1ull));
  int pos = chunk_base[c * E + te] + rank;
  int s = -1;
  if (pos < CAP) {
    token_list[te * CAP + pos] = idx / K_TOP;
    s = te * CAP + pos;
  }
  sid[idx] = s;
}

// ---------------- fused gate+up GEMM -> S = silu(g)*u (bf16) ----------------
// Weights pre-cast+transposed to bf16 [N][K=H]. A and B both staged via
// global_load_lds (linear dest, source-side XOR chunk swizzle -> 0 bank
// conflicts), double-buffered, counted vmcnt(4) before the consume-barrier.
// 128x64 tile, 4 waves 2x2, K-step 32, 4 gload_lds per phase.
__global__ __launch_bounds__(256) void gateup_kernel(
    const short* __restrict__ Xb, const short* __restrict__ Wg, const short* __restrict__ Wu,
    short* __restrict__ Sout, const int* __restrict__ tlist, const int* __restrict__ cnt_dev,
    int Nld, long long wstride, long long sstride) {
  int e = blockIdx.z;
  int cnt = cnt_dev ? cnt_dev[e] : T_TOK;
  int row0 = blockIdx.y * 128;
  if (row0 >= cnt) return;
  int col0 = blockIdx.x * 64;
  const short* wg = Wg + (long long)e * wstride;
  const short* wu = Wu + (long long)e * wstride;
  short* sbase = Sout + (long long)e * sstride;

  __shared__ __align__(16) short As[2][128 * 32];  // 16 KB
  __shared__ __align__(16) short Bgs[2][64 * 32];  // 8 KB
  __shared__ __align__(16) short Bus[2][64 * 32];  // 8 KB

  int tid = threadIdx.x;
  int lane = tid & 63, wave = tid >> 6;

  // staging: row rr (0..63), 16B chunk ch; swizzle applied on SOURCE addr
  int rr = tid >> 2, ch = tid & 3;
  int che = ch ^ ((rr >> 1) & 3);
  int ra0 = row0 + rr, ra1 = ra0 + 64;
  if (tlist) {
    const int* tl = tlist + e * CAP;
    ra0 = tl[min(ra0, cnt - 1)];
    ra1 = tl[min(ra1, cnt - 1)];
  }
  const short* pa0 = Xb + (size_t)ra0 * H + che * 8;
  const short* pa1 = Xb + (size_t)ra1 * H + che * 8;
  const short* pbg = wg + (size_t)(col0 + rr) * H + che * 8;
  const short* pbu = wu + (size_t)(col0 + rr) * H + che * 8;

  short* ldsA00 = &As[0][(wave * 16) * 32];
  short* ldsA10 = &As[0][(64 + wave * 16) * 32];
  short* ldsA01 = &As[1][(wave * 16) * 32];
  short* ldsA11 = &As[1][(64 + wave * 16) * 32];
  short* ldsBg0 = &Bgs[0][(wave * 16) * 32];
  short* ldsBg1 = &Bgs[1][(wave * 16) * 32];
  short* ldsBu0 = &Bus[0][(wave * 16) * 32];
  short* ldsBu1 = &Bus[1][(wave * 16) * 32];

  int wm = wave & 1, wn = wave >> 1;
  int c = lane & 15, q = lane >> 4;
  int qa = q ^ ((c >> 1) & 3);  // swizzled chunk for fragment reads (per-thread const)
  const short* fA0  = &As[0][(wm * 64 + c) * 32 + qa * 8];
  const short* fA1  = &As[1][(wm * 64 + c) * 32 + qa * 8];
  const short* fBg0 = &Bgs[0][(wn * 32 + c) * 32 + qa * 8];
  const short* fBg1 = &Bgs[1][(wn * 32 + c) * 32 + qa * 8];
  const short* fBu0 = &Bus[0][(wn * 32 + c) * 32 + qa * 8];
  const short* fBu1 = &Bus[1][(wn * 32 + c) * 32 + qa * 8];

  f32x4 accg[4][2], accu[4][2];
  #pragma unroll
  for (int i = 0; i < 4; ++i)
    #pragma unroll
    for (int j = 0; j < 2; ++j) {
      accg[i][j] = (f32x4){0.f, 0.f, 0.f, 0.f};
      accu[i][j] = (f32x4){0.f, 0.f, 0.f, 0.f};
    }

  // prologue: stage phase 0 into buf0
  gload_lds16(pa0, ldsA00);
  gload_lds16(pa1, ldsA10);
  gload_lds16(pbg, ldsBg0);
  gload_lds16(pbu, ldsBu0);

// Phase: compute K-slice KC from buf, prefetch KC+32 into other buf.
// 4 gload_lds per phase; vmcnt(4) before the consume-barrier retires the
// previous phase's 4 (incl. the buffer read after the barrier) while keeping
// this phase's 4 in flight across the barrier.
#define GU_PHASE(KC, FAc, FBGc, FBUc, A0d, A1d, BGd, BUd, PREF)                     \
  {                                                                                 \
    __builtin_amdgcn_s_barrier();                                                   \
    asm volatile("" ::: "memory");                                                  \
    if (PREF) {                                                                     \
      gload_lds16(pa0 + (KC) + 32, A0d);                                            \
      gload_lds16(pa1 + (KC) + 32, A1d);                                            \
      gload_lds16(pbg + (KC) + 32, BGd);                                            \
      gload_lds16(pbu + (KC) + 32, BUd);                                            \
      asm volatile("s_waitcnt vmcnt(4)" ::: "memory");                              \
    } else {                                                                        \
      asm volatile("s_waitcnt vmcnt(0)" ::: "memory");                              \
    }                                                                               \
    __builtin_amdgcn_s_barrier();                                                   \
    __builtin_amdgcn_sched_barrier(0);                                              \
    short8v a[4], bg[2], bu[2];                                                     \
    _Pragma("unroll")                                                               \
    for (int mi = 0; mi < 4; ++mi) a[mi] = *(const short8v*)((FAc) + mi * 16 * 32); \
    _Pragma("unroll")                                                               \
    for (int ni = 0; ni < 2; ++ni) {                                                \
      bg[ni] = *(const short8v*)((FBGc) + ni * 16 * 32);                            \
      bu[ni] = *(const short8v*)((FBUc) + ni * 16 * 32);                            \
    }                                                                               \
    _Pragma("unroll")                                                               \
    for (int mi = 0; mi < 4; ++mi)                                                  \
      _Pragma("unroll")                                                             \
      for (int ni = 0; ni < 2; ++ni) {                                              \
        accg[mi][ni] = __builtin_amdgcn_mfma_f32_16x16x32_bf16(a[mi], bg[ni], accg[mi][ni], 0, 0, 0); \
        accu[mi][ni] = __builtin_amdgcn_mfma_f32_16x16x32_bf16(a[mi], bu[ni], accu[mi][ni], 0, 0, 0); \
      }                                                                             \
  }

  for (int k0 = 0; k0 < H; k0 += 64) {
    GU_PHASE(k0,      fA0, fBg0, fBu0, ldsA01, ldsA11, ldsBg1, ldsBu1, true);
    GU_PHASE(k0 + 32, fA1, fBg1, fBu1, ldsA00, ldsA10, ldsBg0, ldsBu0, (k0 + 64 < H));
  }
#undef GU_PHASE

  #pragma unroll
  for (int mi = 0; mi < 4; ++mi) {
    int rbase = row0 + wm * 64 + mi * 16 + q * 4;
    #pragma unroll
    for (int ni = 0; ni < 2; ++ni) {
      int col = col0 + wn * 32 + ni * 16 + c;
      #pragma unroll
      for (int r = 0; r < 4; ++r) {
        float g = accg[mi][ni][r], u = accu[mi][ni][r];
        float s = (g / (1.f + __expf(-g))) * u;
        sbase[(size_t)(rbase + r) * Nld + col] = (short)f2bfbits(s);
      }
    }
  }
}

// ---------------- down GEMM: Y = S @ Wdt (bf16 [N=H][K] transposed) ----------------
// Same pipelined pure-gload_lds structure; 128x128 tile, 4 gload_lds/phase.
__global__ __launch_bounds__(256) void down_kernel(
    const short* __restrict__ Sin, const short* __restrict__ Wd,
    float* __restrict__ outF, short* __restrict__ outY,
    const int* __restrict__ cnt_dev, int Kdim, long long wstride, long long sstride) {
  int e = blockIdx.z;
  int cnt = cnt_dev ? cnt_dev[e] : T_TOK;
  int row0 = blockIdx.y * 128;
  if (row0 >= cnt) return;
  int col0 = blockIdx.x * 128;
  const short* sb = Sin + (long long)e * sstride;
  const short* wd = Wd + (long long)e * wstride;

  __shared__ __align__(16) short As[2][128 * 32];  // 16 KB
  __shared__ __align__(16) short Bs[2][128 * 32];  // 16 KB

  int tid = threadIdx.x;
  int lane = tid & 63, wave = tid >> 6;
  int rr = tid >> 2, ch = tid & 3;
  int che = ch ^ ((rr >> 1) & 3);

  const short* pa0 = sb + (size_t)(row0 + rr) * Kdim + che * 8;
  const short* pa1 = pa0 + (size_t)64 * Kdim;
  const short* pb0 = wd + (size_t)(col0 + rr) * Kdim + che * 8;
  const short* pb1 = pb0 + (size_t)64 * Kdim;

  short* ldsA00 = &As[0][(wave * 16) * 32];
  short* ldsA10 = &As[0][(64 + wave * 16) * 32];
  short* ldsA01 = &As[1][(wave * 16) * 32];
  short* ldsA11 = &As[1][(64 + wave * 16) * 32];
  short* ldsB00 = &Bs[0][(wave * 16) * 32];
  short* ldsB10 = &Bs[0][(64 + wave * 16) * 32];
  short* ldsB01 = &Bs[1][(wave * 16) * 32];
  short* ldsB11 = &Bs[1][(64 + wave * 16) * 32];

  int wm = wave & 1, wn = wave >> 1;
  int c = lane & 15, q = lane >> 4;
  int qa = q ^ ((c >> 1) & 3);
  const short* fA0 = &As[0][(wm * 64 + c) * 32 + qa * 8];
  const short* fA1 = &As[1][(wm * 64 + c) * 32 + qa * 8];
  const short* fB0 = &Bs[0][(wn * 64 + c) * 32 + qa * 8];
  const short* fB1 = &Bs[1][(wn * 64 + c) * 32 + qa * 8];

  f32x4 acc[4][4];
  #pragma unroll
  for (int i = 0; i < 4; ++i)
    #pragma unroll
    for (int j = 0; j < 4; ++j) acc[i][j] = (f32x4){0.f, 0.f, 0.f, 0.f};

  gload_lds16(pa0, ldsA00);
  gload_lds16(pa1, ldsA10);
  gload_lds16(pb0, ldsB00);
  gload_lds16(pb1, ldsB10);

#define DN_PHASE(KC, FAc, FBc, A0d, A1d, B0d, B1d, PREF)                            \
  {                                                                                 \
    __builtin_amdgcn_s_barrier();                                                   \
    asm volatile("" ::: "memory");                                                  \
    if (PREF) {                                                                     \
      gload_lds16(pa0 + (KC) + 32, A0d);                                            \
      gload_lds16(pa1 + (KC) + 32, A1d);                                            \
      gload_lds16(pb0 + (KC) + 32, B0d);                                            \
      gload_lds16(pb1 + (KC) + 32, B1d);                                            \
      asm volatile("s_waitcnt vmcnt(4)" ::: "memory");                              \
    } else {                                                                        \
      asm volatile("s_waitcnt vmcnt(0)" ::: "memory");                              \
    }                                                                               \
    __builtin_amdgcn_s_barrier();                                                   \
    __builtin_amdgcn_sched_barrier(0);                                              \
    short8v a[4], b[4];                                                             \
    _Pragma("unroll")                                                               \
    for (int mi = 0; mi < 4; ++mi) a[mi] = *(const short8v*)((FAc) + mi * 16 * 32); \
    _Pragma("unroll")                                                               \
    for (int ni = 0; ni < 4; ++ni) b[ni] = *(const short8v*)((FBc) + ni * 16 * 32); \
    _Pragma("unroll")                                                               \
    for (int mi = 0; mi < 4; ++mi)                                                  \
      _Pragma("unroll")                                                             \
      for (int ni = 0; ni < 4; ++ni)                                                \
        acc[mi][ni] = __builtin_amdgcn_mfma_f32_16x16x32_bf16(a[mi], b[ni], acc[mi][ni], 0, 0, 0); \
  }

  for (int k0 = 0; k0 < Kdim; k0 += 64) {
    DN_PHASE(k0,      fA0, fB0, ldsA01, ldsA11, ldsB01, ldsB11, true);
    DN_PHASE(k0 + 32, fA1, fB1, ldsA00, ldsA10, ldsB00, ldsB10, (k0 + 64 < Kdim));
  }
#undef DN_PHASE

  if (outY) {
    #pragma unroll
    for (int mi = 0; mi < 4; ++mi) {
      int rb = row0 + wm * 64 + mi * 16 + q * 4;
      #pragma unroll
      for (int r = 0; r < 4; ++r) {
        short* yrow = outY + (size_t)(e * CAP + rb + r) * H;
        #pragma unroll
        for (int ni = 0; ni < 4; ++ni) {
          int col = col0 + wn * 64 + ni * 16 + c;
          yrow[col] = (short)f2bfbits(acc[mi][ni][r]);
        }
      }
    }
  } else {
    #pragma unroll
    for (int mi = 0; mi < 4; ++mi) {
      int rb = row0 + wm * 64 + mi * 16 + q * 4;
      #pragma unroll
      for (int ni = 0; ni < 4; ++ni) {
        int col = col0 + wn * 64 + ni * 16 + c;
        #pragma unroll
        for (int r = 0; r < 4; ++r)
          outF[(size_t)(rb + r) * H + col] = acc[mi][ni][r];
      }
    }
  }
}

// ---------------- combine: out[t] += sum_k w_k * Yr[sid_k] ----------------
__global__ __launch_bounds__(256) void combine_kernel(
    const short* __restrict__ Yr, const int* __restrict__ sid,
    const float* __restrict__ twt, float* __restrict__ out) {
  int t = blockIdx.x;
  int col = threadIdx.x * 4;
  float* op = out + (size_t)t * H + col;
  float4 o = *(float4*)op;
  #pragma unroll
  for (int k = 0; k < K_TOP; ++k) {
    int s = sid[t * K_TOP + k];
    if (s >= 0) {
      float w = twt[t * K_TOP + k];
      ushort4 y = *(const ushort4*)(Yr + (size_t)s * H + col);
      o.x += w * bf2f(y.x);
      o.y += w * bf2f(y.y);
      o.z += w * bf2f(y.z);
      o.w += w * bf2f(y.w);
    }
  }
  *(float4*)op = o;
}

extern "C" void kernel_launch(void* const* d_in, const int* in_sizes, int n_in,
                              void* d_out, int out_size, void* d_ws, size_t ws_size,
                              hipStream_t stream) {
  const float* x       = (const float*)d_in[0];
  const float* gate_w  = (const float*)d_in[1];
  const float* w_gate  = (const float*)d_in[2];
  const float* w_up    = (const float*)d_in[3];
  const float* w_down  = (const float*)d_in[4];
  const float* sw_gate = (const float*)d_in[5];
  const float* sw_up   = (const float*)d_in[6];
  const float* sw_down = (const float*)d_in[7];
  float* out = (float*)d_out;
  char* ws = (char*)d_ws;

  size_t o = 0;
  short* xb   = (short*)(ws + o); o += (size_t)T_TOK * H * 2;            // 4 MB
  short* Sr   = (short*)(ws + o); o += (size_t)E * CAP * I_DIM * 2;      // 34.6 MB
  short* Ss   = (short*)(ws + o); o += (size_t)T_TOK * IS_DIM * 2;       // 5.8 MB
  // wg_t+wu_t region (92.2 MB) is dead after routed gateup; Yr (50.3 MB)
  // aliases it (routed down runs strictly after routed gateup in-stream).
  short* wg_t = (short*)(ws + o);
  short* Yr   = (short*)(ws + o); o += (size_t)E * H * I_DIM * 2;        // 46.1 MB
  short* wu_t = (short*)(ws + o); o += (size_t)E * H * I_DIM * 2;        // 46.1 MB
  short* wd_t = (short*)(ws + o); o += (size_t)E * I_DIM * H * 2;        // 46.1 MB
  short* swg_t = (short*)(ws + o); o += (size_t)H * IS_DIM * 2;          // 2.9 MB
  short* swu_t = (short*)(ws + o); o += (size_t)H * IS_DIM * 2;          // 2.9 MB
  short* swd_t = (short*)(ws + o); o += (size_t)IS_DIM * H * 2;          // 2.9 MB
  int*   tidx = (int*)(ws + o);   o += (size_t)T_TOK * K_TOP * 4;
  float* twt  = (float*)(ws + o); o += (size_t)T_TOK * K_TOP * 4;
  int*   sid  = (int*)(ws + o);   o += (size_t)T_TOK * K_TOP * 4;
  int*   tl   = (int*)(ws + o);   o += (size_t)E * CAP * 4;
  int*   cnt  = (int*)(ws + o);   o += 256;
  int*   chist = (int*)(ws + o);  o += (size_t)NCHUNK * E * 4;
  int*   cbase = (int*)(ws + o);  o += (size_t)NCHUNK * E * 4;

  cast_x_kernel<<<(T_TOK * H) / 1024, 256, 0, stream>>>(x, xb);
  gating_kernel<<<T_TOK, 64, 0, stream>>>(x, gate_w, tidx, twt);
  hist_kernel<<<NCHUNK, 64, 0, stream>>>(tidx, chist);
  scan_kernel<<<1, 1024, 0, stream>>>(chist, cbase, cnt);
  place_kernel<<<NCHUNK, 64, 0, stream>>>(tidx, cbase, tl, sid);

  // cast+transpose all weights to bf16 [N][K]
  tw_kernel<<<dim3(I_DIM / 64, H / 64, E), 256, 0, stream>>>(w_gate, wg_t, H, I_DIM);
  tw_kernel<<<dim3(I_DIM / 64, H / 64, E), 256, 0, stream>>>(w_up,   wu_t, H, I_DIM);
  tw_kernel<<<dim3(H / 64, I_DIM / 64, E), 256, 0, stream>>>(w_down, wd_t, I_DIM, H);
  tw_kernel<<<dim3(IS_DIM / 64, H / 64, 1), 256, 0, stream>>>(sw_gate, swg_t, H, IS_DIM);
  tw_kernel<<<dim3(IS_DIM / 64, H / 64, 1), 256, 0, stream>>>(sw_up,   swu_t, H, IS_DIM);
  tw_kernel<<<dim3(H / 64, IS_DIM / 64, 1), 256, 0, stream>>>(sw_down, swd_t, IS_DIM, H);

  // routed gate+up -> Sr  (reads wg_t/wu_t; must finish before Yr alias is written)
  gateup_kernel<<<dim3(I_DIM / 64, CAP / 128, E), 256, 0, stream>>>(
      xb, wg_t, wu_t, Sr, tl, cnt, I_DIM, (long long)H * I_DIM, (long long)CAP * I_DIM);
  // shared gate+up -> Ss
  gateup_kernel<<<dim3(IS_DIM / 64, T_TOK / 128, 1), 256, 0, stream>>>(
      xb, swg_t, swu_t, Ss, nullptr, nullptr, IS_DIM, 0, 0);
  // shared down: fp32 store, fully initializes out
  down_kernel<<<dim3(H / 128, T_TOK / 128, 1), 256, 0, stream>>>(
      Ss, swd_t, out, nullptr, nullptr, IS_DIM, 0, 0);
  // routed down: bf16 stores into slot buffer (Yr aliases wg_t region — safe now)
  down_kernel<<<dim3(H / 128, CAP / 128, E), 256, 0, stream>>>(
      Sr, wd_t, nullptr, Yr, cnt, I_DIM, (long long)I_DIM * H, (long long)CAP * I_DIM);
  // final combine
  combine_kernel<<<T_TOK, 256, 0, stream>>>(Yr, sid, twt, out);
}

// Round 4
// 539.387 us; speedup vs baseline: 1.0166x; 1.0166x over previous
//
#include <hip/hip_runtime.h>
#include <hip/hip_bf16.h>

#define H 1024
#define I_DIM 704
#define E 32
#define TOPK_GROUP 3
#define K_TOP 6
#define T_TOK 2048
#define CAP 768
#define IS_DIM 1408   // N_SHARED * I
#define NCHUNK 192    // (T_TOK*K_TOP)/64

typedef __attribute__((ext_vector_type(8))) short short8v;
typedef __attribute__((ext_vector_type(4))) float f32x4;

__device__ __forceinline__ unsigned short f2bfbits(float f) {
  unsigned u = __float_as_uint(f);
  unsigned r = (u + 0x7fffu + ((u >> 16) & 1u)) >> 16;  // RTNE
  return (unsigned short)r;
}
__device__ __forceinline__ float bf2f(unsigned short b) {
  return __uint_as_float(((unsigned)b) << 16);
}
__device__ __forceinline__ void gload_lds16(const short* g, short* l) {
  __builtin_amdgcn_global_load_lds(
      (const __attribute__((address_space(1))) unsigned int*)g,
      (__attribute__((address_space(3))) unsigned int*)l, 16, 0, 0);
}

// ---------------- cast x (fp32) -> bf16 bits ----------------
__global__ void cast_x_kernel(const float* __restrict__ x, short* __restrict__ xb) {
  size_t i = ((size_t)blockIdx.x * 256 + threadIdx.x) * 4;
  float4 v = *(const float4*)(x + i);
  short4 s;
  s.x = (short)f2bfbits(v.x); s.y = (short)f2bfbits(v.y);
  s.z = (short)f2bfbits(v.z); s.w = (short)f2bfbits(v.w);
  *(short4*)(xb + i) = s;
}

// ---------------- cast+transpose weights: in fp32 [K][N] -> out bf16 [N][K] ----------------
__global__ __launch_bounds__(256) void tw_kernel(const float* __restrict__ in,
                                                 short* __restrict__ out,
                                                 int K, int N) {
  __shared__ float tile[64][65];
  long long eoff = (long long)blockIdx.z * (long long)K * N;
  const float* ip = in + eoff;
  short* op = out + eoff;
  int n0 = blockIdx.x * 64, k0 = blockIdx.y * 64;
  int t = threadIdx.x;
  int tr = t >> 4;          // 0..15
  int tc = (t & 15) * 4;    // 0..60
  #pragma unroll
  for (int i = 0; i < 4; ++i) {
    float4 v = *(const float4*)(ip + (size_t)(k0 + tr + i * 16) * N + n0 + tc);
    tile[tr + i * 16][tc + 0] = v.x;
    tile[tr + i * 16][tc + 1] = v.y;
    tile[tr + i * 16][tc + 2] = v.z;
    tile[tr + i * 16][tc + 3] = v.w;
  }
  __syncthreads();
  #pragma unroll
  for (int i = 0; i < 4; ++i) {
    int n = tr + i * 16;
    short4 s;
    s.x = (short)f2bfbits(tile[tc + 0][n]);
    s.y = (short)f2bfbits(tile[tc + 1][n]);
    s.z = (short)f2bfbits(tile[tc + 2][n]);
    s.w = (short)f2bfbits(tile[tc + 3][n]);
    *(short4*)(op + (size_t)(n0 + n) * K + k0 + tc) = s;
  }
}

// ---------------- gating: fp64 logits, lane-parallel softmax + group top-3 + top-6 ----------------
__global__ __launch_bounds__(64) void gating_kernel(const float* __restrict__ x,
                                                    const float* __restrict__ gw,
                                                    int* __restrict__ tidx,
                                                    float* __restrict__ tw) {
  int t = blockIdx.x;
  int lane = threadIdx.x;
  int e = lane & 31, half = lane >> 5;
  const float4* xr4 = (const float4*)(x + (size_t)t * H + half * 512);
  const float4* wr4 = (const float4*)(gw + (size_t)e * H + half * 512);
  double acc = 0.0;
  #pragma unroll 4
  for (int j = 0; j < 128; ++j) {
    float4 a = xr4[j], b = wr4[j];
    acc += (double)a.x * b.x + (double)a.y * b.y + (double)a.z * b.z + (double)a.w * b.w;
  }
  acc += __shfl_down(acc, 32);   // lanes 0..31 hold the 32 logits
  double lg = acc;
  double m = lg;
  #pragma unroll
  for (int off = 16; off >= 1; off >>= 1) {
    double o = __shfl_xor(m, off);
    if (o > m) m = o;
  }
  double p = exp(lg - m);
  double sum = p;
  #pragma unroll
  for (int off = 16; off >= 1; off >>= 1) sum += __shfl_xor(sum, off);
  p /= sum;
  double gmax = p;
  { double o = __shfl_xor(gmax, 1); if (o > gmax) gmax = o;
    o = __shfl_xor(gmax, 2); if (o > gmax) gmax = o; }
  bool gsel = false;
  double gv = gmax;
  #pragma unroll
  for (int it = 0; it < TOPK_GROUP; ++it) {
    double v = gv; int gi = e >> 2;
    #pragma unroll
    for (int off = 16; off >= 1; off >>= 1) {
      double ov = __shfl_xor(v, off);
      int oi = __shfl_xor(gi, off);
      if (ov > v || (ov == v && oi < gi)) { v = ov; gi = oi; }
    }
    if ((e >> 2) == gi) { gsel = true; gv = -1e300; }
  }
  double mp = gsel ? p : 0.0;
  #pragma unroll
  for (int it = 0; it < K_TOP; ++it) {
    double v = mp; int ei = e;
    #pragma unroll
    for (int off = 16; off >= 1; off >>= 1) {
      double ov = __shfl_xor(v, off);
      int oi = __shfl_xor(ei, off);
      if (ov > v || (ov == v && oi < ei)) { v = ov; ei = oi; }
    }
    if (lane == 0) { tidx[t * K_TOP + it] = ei; tw[t * K_TOP + it] = (float)v; }
    if (e == ei) mp = -2.0;
  }
}

// ---------------- dispatch phase 1: per-chunk histograms ----------------
__global__ __launch_bounds__(64) void hist_kernel(const int* __restrict__ tidx,
                                                  int* __restrict__ chunk_hist) {
  __shared__ int h[E];
  int c = blockIdx.x, lane = threadIdx.x;
  if (lane < E) h[lane] = 0;
  __syncthreads();
  int te = tidx[c * 64 + lane];
  atomicAdd(&h[te], 1);
  __syncthreads();
  if (lane < E) chunk_hist[c * E + lane] = h[lane];
}

// ---------------- dispatch phase 2: per-expert exclusive prefix over chunks ----------------
__global__ __launch_bounds__(1024) void scan_kernel(const int* __restrict__ chunk_hist,
                                                    int* __restrict__ chunk_base,
                                                    int* __restrict__ cnt) {
  __shared__ int h[NCHUNK * E];  // 24 KB
  int t = threadIdx.x;
  for (int i = t; i < NCHUNK * E; i += 1024) h[i] = chunk_hist[i];
  __syncthreads();
  if (t < E) {
    int run = 0;
    for (int c = 0; c < NCHUNK; ++c) {
      int v = h[c * E + t];
      h[c * E + t] = run;
      run += v;
    }
    cnt[t] = run < CAP ? run : CAP;
  }
  __syncthreads();
  for (int i = t; i < NCHUNK * E; i += 1024) chunk_base[i] = h[i];
}

// ---------------- dispatch phase 3: placement + inverse slot map ----------------
__global__ __launch_bounds__(64) void place_kernel(const int* __restrict__ tidx,
                                                   const int* __restrict__ chunk_base,
                                                   int* __restrict__ token_list,
                                                   int* __restrict__ sid) {
  int c = blockIdx.x, lane = threadIdx.x;
  int idx = c * 64 + lane;
  int te = tidx[idx];
  unsigned long long mymask = 0;
  #pragma unroll
  for (int e = 0; e < E; ++e) {
    unsigned long long bal = __ballot(te == e);
    if (te == e) mymask = bal;
  }
  int rank = __popcll(mymask & ((1ull << lane) - 1ull));
  int pos = chunk_base[c * E + te] + rank;
  int s = -1;
  if (pos < CAP) {
    token_list[te * CAP + pos] = idx / K_TOP;
    s = te * CAP + pos;
  }
  sid[idx] = s;
}

// ---------------- fused gate+up GEMM -> S = silu(g)*u (bf16) ----------------
// bf16 [N][K] weights. Triple-buffered LDS, prefetch distance 2 (phase p
// stages p+2), counted vmcnt(8) before the consume-barrier; tail phases
// keep the count uniform via clamped dummy stages into dead buffers.
// Source-side XOR chunk swizzle -> 0 bank conflicts. setprio around MFMA.
// Routed launches get an XCD-cluster block remap (4 experts/XCD, y-fastest).
__global__ __launch_bounds__(256) void gateup_kernel(
    const short* __restrict__ Xb, const short* __restrict__ Wg, const short* __restrict__ Wu,
    short* __restrict__ Sout, const int* __restrict__ tlist, const int* __restrict__ cnt_dev,
    int Nld, long long wstride, long long sstride) {
  int bx = blockIdx.x, by = blockIdx.y, bz = blockIdx.z;
  if (tlist) {  // routed: total blocks divisible by 8 -> bijective XCD remap
    int gx = gridDim.x, gy = gridDim.y;
    int total = gx * gy * gridDim.z;
    int cpx = total >> 3;
    int lin = bx + gx * (by + gy * bz);
    int lin2 = (lin & 7) * cpx + (lin >> 3);
    int pe = gx * gy;
    bz = lin2 / pe;
    int r = lin2 % pe;
    by = r % gy;   // y fastest: consecutive blocks share the W col-panel (L2)
    bx = r / gy;
  }
  int e = bz;
  int cnt = cnt_dev ? cnt_dev[e] : T_TOK;
  int row0 = by * 128;
  if (row0 >= cnt) return;
  int col0 = bx * 64;
  const short* wg = Wg + (long long)e * wstride;
  const short* wu = Wu + (long long)e * wstride;
  short* sbase = Sout + (long long)e * sstride;

  __shared__ __align__(16) short As[3][128 * 32];  // 24 KB
  __shared__ __align__(16) short Bgs[3][64 * 32];  // 12 KB
  __shared__ __align__(16) short Bus[3][64 * 32];  // 12 KB

  int tid = threadIdx.x;
  int lane = tid & 63, wave = tid >> 6;

  // staging: row rr (0..63), 16B chunk ch; swizzle applied on SOURCE addr
  int rr = tid >> 2, ch = tid & 3;
  int che = ch ^ ((rr >> 1) & 3);
  int ra0 = row0 + rr, ra1 = ra0 + 64;
  if (tlist) {
    const int* tl = tlist + e * CAP;
    ra0 = tl[min(ra0, cnt - 1)];
    ra1 = tl[min(ra1, cnt - 1)];
  }
  const short* pa0 = Xb + (size_t)ra0 * H + che * 8;
  const short* pa1 = Xb + (size_t)ra1 * H + che * 8;
  const short* pbg = wg + (size_t)(col0 + rr) * H + che * 8;
  const short* pbu = wu + (size_t)(col0 + rr) * H + che * 8;

  int wm = wave & 1, wn = wave >> 1;
  int c = lane & 15, q = lane >> 4;
  int qa = q ^ ((c >> 1) & 3);  // swizzled chunk for fragment reads

  f32x4 accg[4][2], accu[4][2];
  #pragma unroll
  for (int i = 0; i < 4; ++i)
    #pragma unroll
    for (int j = 0; j < 2; ++j) {
      accg[i][j] = (f32x4){0.f, 0.f, 0.f, 0.f};
      accu[i][j] = (f32x4){0.f, 0.f, 0.f, 0.f};
    }

#define STAGE_GU(KK, B)                                       \
  gload_lds16(pa0 + (KK), &As[B][(wave * 16) * 32]);          \
  gload_lds16(pa1 + (KK), &As[B][(64 + wave * 16) * 32]);     \
  gload_lds16(pbg + (KK), &Bgs[B][(wave * 16) * 32]);         \
  gload_lds16(pbu + (KK), &Bus[B][(wave * 16) * 32]);

  // prologue: stage phases 0,1 (order matters for in-order vmcnt retirement)
  STAGE_GU(0, 0)
  STAGE_GU(32, 1)

// Phase: compute K-slice KC from buf B, stage KC+64 into buf NB=(B+2)%3.
// 4 gloads/wave/phase; outstanding at the wait = 12 -> vmcnt(8) retires
// exactly this phase's 4. Clamped kk keeps the count uniform at the tail.
#define GU_PHASE(KC, B, NB)                                                          \
  {                                                                                  \
    __builtin_amdgcn_s_barrier();                                                    \
    asm volatile("" ::: "memory");                                                   \
    { int kk = (KC) + 64; if (kk >= H) kk = 0;                                       \
      STAGE_GU(kk, NB) }                                                             \
    asm volatile("s_waitcnt vmcnt(8)" ::: "memory");                                 \
    __builtin_amdgcn_s_barrier();                                                    \
    __builtin_amdgcn_sched_barrier(0);                                               \
    short8v a[4], bg[2], bu[2];                                                      \
    _Pragma("unroll")                                                                \
    for (int mi = 0; mi < 4; ++mi)                                                   \
      a[mi] = *(const short8v*)(&As[B][(wm * 64 + mi * 16 + c) * 32 + qa * 8]);      \
    _Pragma("unroll")                                                                \
    for (int ni = 0; ni < 2; ++ni) {                                                 \
      bg[ni] = *(const short8v*)(&Bgs[B][(wn * 32 + ni * 16 + c) * 32 + qa * 8]);    \
      bu[ni] = *(const short8v*)(&Bus[B][(wn * 32 + ni * 16 + c) * 32 + qa * 8]);    \
    }                                                                                \
    __builtin_amdgcn_s_setprio(1);                                                   \
    _Pragma("unroll")                                                                \
    for (int mi = 0; mi < 4; ++mi)                                                   \
      _Pragma("unroll")                                                              \
      for (int ni = 0; ni < 2; ++ni) {                                               \
        accg[mi][ni] = __builtin_amdgcn_mfma_f32_16x16x32_bf16(a[mi], bg[ni], accg[mi][ni], 0, 0, 0); \
        accu[mi][ni] = __builtin_amdgcn_mfma_f32_16x16x32_bf16(a[mi], bu[ni], accu[mi][ni], 0, 0, 0); \
      }                                                                              \
    __builtin_amdgcn_s_setprio(0);                                                   \
  }

  // H/32 = 32 phases = 10 triples + 2 tail phases
  for (int k0 = 0; k0 < 960; k0 += 96) {
    GU_PHASE(k0, 0, 2)
    GU_PHASE(k0 + 32, 1, 0)
    GU_PHASE(k0 + 64, 2, 1)
  }
  GU_PHASE(960, 0, 2)
  GU_PHASE(992, 1, 0)
#undef GU_PHASE
#undef STAGE_GU
  asm volatile("s_waitcnt vmcnt(0)" ::: "memory");  // drain dummy stages before LDS release

  #pragma unroll
  for (int mi = 0; mi < 4; ++mi) {
    int rbase = row0 + wm * 64 + mi * 16 + q * 4;
    #pragma unroll
    for (int ni = 0; ni < 2; ++ni) {
      int col = col0 + wn * 32 + ni * 16 + c;
      #pragma unroll
      for (int r = 0; r < 4; ++r) {
        float g = accg[mi][ni][r], u = accu[mi][ni][r];
        float s = (g / (1.f + __expf(-g))) * u;
        sbase[(size_t)(rbase + r) * Nld + col] = (short)f2bfbits(s);
      }
    }
  }
}

// ---------------- down GEMM: Y = S @ Wdt (bf16 [N=H][K]) ----------------
// Same triple-buffered depth-2 pipeline; 128x128 tile.
__global__ __launch_bounds__(256) void down_kernel(
    const short* __restrict__ Sin, const short* __restrict__ Wd,
    float* __restrict__ outF, short* __restrict__ outY,
    const int* __restrict__ cnt_dev, int Kdim, long long wstride, long long sstride) {
  int bx = blockIdx.x, by = blockIdx.y, bz = blockIdx.z;
  if (cnt_dev) {  // routed: XCD remap
    int gx = gridDim.x, gy = gridDim.y;
    int total = gx * gy * gridDim.z;
    int cpx = total >> 3;
    int lin = bx + gx * (by + gy * bz);
    int lin2 = (lin & 7) * cpx + (lin >> 3);
    int pe = gx * gy;
    bz = lin2 / pe;
    int r = lin2 % pe;
    by = r % gy;
    bx = r / gy;
  }
  int e = bz;
  int cnt = cnt_dev ? cnt_dev[e] : T_TOK;
  int row0 = by * 128;
  if (row0 >= cnt) return;
  int col0 = bx * 128;
  const short* sb = Sin + (long long)e * sstride;
  const short* wd = Wd + (long long)e * wstride;

  __shared__ __align__(16) short As[3][128 * 32];  // 24 KB
  __shared__ __align__(16) short Bs[3][128 * 32];  // 24 KB

  int tid = threadIdx.x;
  int lane = tid & 63, wave = tid >> 6;
  int rr = tid >> 2, ch = tid & 3;
  int che = ch ^ ((rr >> 1) & 3);

  const short* pa0 = sb + (size_t)(row0 + rr) * Kdim + che * 8;
  const short* pa1 = pa0 + (size_t)64 * Kdim;
  const short* pb0 = wd + (size_t)(col0 + rr) * Kdim + che * 8;
  const short* pb1 = pb0 + (size_t)64 * Kdim;

  int wm = wave & 1, wn = wave >> 1;
  int c = lane & 15, q = lane >> 4;
  int qa = q ^ ((c >> 1) & 3);

  f32x4 acc[4][4];
  #pragma unroll
  for (int i = 0; i < 4; ++i)
    #pragma unroll
    for (int j = 0; j < 4; ++j) acc[i][j] = (f32x4){0.f, 0.f, 0.f, 0.f};

#define STAGE_DN(KK, B)                                       \
  gload_lds16(pa0 + (KK), &As[B][(wave * 16) * 32]);          \
  gload_lds16(pa1 + (KK), &As[B][(64 + wave * 16) * 32]);     \
  gload_lds16(pb0 + (KK), &Bs[B][(wave * 16) * 32]);          \
  gload_lds16(pb1 + (KK), &Bs[B][(64 + wave * 16) * 32]);

  STAGE_DN(0, 0)
  STAGE_DN(32, 1)

#define DN_PHASE(KC, B, NB)                                                          \
  {                                                                                  \
    __builtin_amdgcn_s_barrier();                                                    \
    asm volatile("" ::: "memory");                                                   \
    { int kk = (KC) + 64; if (kk >= Kdim) kk = 0;                                    \
      STAGE_DN(kk, NB) }                                                             \
    asm volatile("s_waitcnt vmcnt(8)" ::: "memory");                                 \
    __builtin_amdgcn_s_barrier();                                                    \
    __builtin_amdgcn_sched_barrier(0);                                               \
    short8v a[4], b[4];                                                              \
    _Pragma("unroll")                                                                \
    for (int mi = 0; mi < 4; ++mi)                                                   \
      a[mi] = *(const short8v*)(&As[B][(wm * 64 + mi * 16 + c) * 32 + qa * 8]);      \
    _Pragma("unroll")                                                                \
    for (int ni = 0; ni < 4; ++ni)                                                   \
      b[ni] = *(const short8v*)(&Bs[B][(wn * 64 + ni * 16 + c) * 32 + qa * 8]);      \
    __builtin_amdgcn_s_setprio(1);                                                   \
    _Pragma("unroll")                                                                \
    for (int mi = 0; mi < 4; ++mi)                                                   \
      _Pragma("unroll")                                                              \
      for (int ni = 0; ni < 4; ++ni)                                                 \
        acc[mi][ni] = __builtin_amdgcn_mfma_f32_16x16x32_bf16(a[mi], b[ni], acc[mi][ni], 0, 0, 0); \
    __builtin_amdgcn_s_setprio(0);                                                   \
  }

  // Kdim/32 phases = ntr triples + tail (1 or 2); buffers cycle 0,1,2 strictly
  {
    int nph = Kdim >> 5;
    int ntr = nph / 3;
    int tail = nph - ntr * 3;
    int k0 = 0;
    for (int t3 = 0; t3 < ntr; ++t3, k0 += 96) {
      DN_PHASE(k0, 0, 2)
      DN_PHASE(k0 + 32, 1, 0)
      DN_PHASE(k0 + 64, 2, 1)
    }
    if (tail >= 1) { DN_PHASE(k0, 0, 2) }
    if (tail >= 2) { DN_PHASE(k0 + 32, 1, 0) }
  }
#undef DN_PHASE
#undef STAGE_DN
  asm volatile("s_waitcnt vmcnt(0)" ::: "memory");

  if (outY) {
    #pragma unroll
    for (int mi = 0; mi < 4; ++mi) {
      int rb = row0 + wm * 64 + mi * 16 + q * 4;
      #pragma unroll
      for (int r = 0; r < 4; ++r) {
        short* yrow = outY + (size_t)(e * CAP + rb + r) * H;
        #pragma unroll
        for (int ni = 0; ni < 4; ++ni) {
          int col = col0 + wn * 64 + ni * 16 + c;
          yrow[col] = (short)f2bfbits(acc[mi][ni][r]);
        }
      }
    }
  } else {
    #pragma unroll
    for (int mi = 0; mi < 4; ++mi) {
      int rb = row0 + wm * 64 + mi * 16 + q * 4;
      #pragma unroll
      for (int ni = 0; ni < 4; ++ni) {
        int col = col0 + wn * 64 + ni * 16 + c;
        #pragma unroll
        for (int r = 0; r < 4; ++r)
          outF[(size_t)(rb + r) * H + col] = acc[mi][ni][r];
      }
    }
  }
}

// ---------------- combine: out[t] += sum_k w_k * Yr[sid_k] ----------------
__global__ __launch_bounds__(256) void combine_kernel(
    const short* __restrict__ Yr, const int* __restrict__ sid,
    const float* __restrict__ twt, float* __restrict__ out) {
  int t = blockIdx.x;
  int col = threadIdx.x * 4;
  float* op = out + (size_t)t * H + col;
  float4 o = *(float4*)op;
  #pragma unroll
  for (int k = 0; k < K_TOP; ++k) {
    int s = sid[t * K_TOP + k];
    if (s >= 0) {
      float w = twt[t * K_TOP + k];
      ushort4 y = *(const ushort4*)(Yr + (size_t)s * H + col);
      o.x += w * bf2f(y.x);
      o.y += w * bf2f(y.y);
      o.z += w * bf2f(y.z);
      o.w += w * bf2f(y.w);
    }
  }
  *(float4*)op = o;
}

extern "C" void kernel_launch(void* const* d_in, const int* in_sizes, int n_in,
                              void* d_out, int out_size, void* d_ws, size_t ws_size,
                              hipStream_t stream) {
  const float* x       = (const float*)d_in[0];
  const float* gate_w  = (const float*)d_in[1];
  const float* w_gate  = (const float*)d_in[2];
  const float* w_up    = (const float*)d_in[3];
  const float* w_down  = (const float*)d_in[4];
  const float* sw_gate = (const float*)d_in[5];
  const float* sw_up   = (const float*)d_in[6];
  const float* sw_down = (const float*)d_in[7];
  float* out = (float*)d_out;
  char* ws = (char*)d_ws;

  size_t o = 0;
  short* xb   = (short*)(ws + o); o += (size_t)T_TOK * H * 2;            // 4 MB
  short* Sr   = (short*)(ws + o); o += (size_t)E * CAP * I_DIM * 2;      // 34.6 MB
  short* Ss   = (short*)(ws + o); o += (size_t)T_TOK * IS_DIM * 2;       // 5.8 MB
  // wg_t+wu_t region is dead after routed gateup; Yr aliases it.
  short* wg_t = (short*)(ws + o);
  short* Yr   = (short*)(ws + o); o += (size_t)E * H * I_DIM * 2;        // 46.1 MB
  short* wu_t = (short*)(ws + o); o += (size_t)E * H * I_DIM * 2;        // 46.1 MB
  short* wd_t = (short*)(ws + o); o += (size_t)E * I_DIM * H * 2;        // 46.1 MB
  short* swg_t = (short*)(ws + o); o += (size_t)H * IS_DIM * 2;          // 2.9 MB
  short* swu_t = (short*)(ws + o); o += (size_t)H * IS_DIM * 2;          // 2.9 MB
  short* swd_t = (short*)(ws + o); o += (size_t)IS_DIM * H * 2;          // 2.9 MB
  int*   tidx = (int*)(ws + o);   o += (size_t)T_TOK * K_TOP * 4;
  float* twt  = (float*)(ws + o); o += (size_t)T_TOK * K_TOP * 4;
  int*   sid  = (int*)(ws + o);   o += (size_t)T_TOK * K_TOP * 4;
  int*   tl   = (int*)(ws + o);   o += (size_t)E * CAP * 4;
  int*   cnt  = (int*)(ws + o);   o += 256;
  int*   chist = (int*)(ws + o);  o += (size_t)NCHUNK * E * 4;
  int*   cbase = (int*)(ws + o);  o += (size_t)NCHUNK * E * 4;

  cast_x_kernel<<<(T_TOK * H) / 1024, 256, 0, stream>>>(x, xb);
  gating_kernel<<<T_TOK, 64, 0, stream>>>(x, gate_w, tidx, twt);
  hist_kernel<<<NCHUNK, 64, 0, stream>>>(tidx, chist);
  scan_kernel<<<1, 1024, 0, stream>>>(chist, cbase, cnt);
  place_kernel<<<NCHUNK, 64, 0, stream>>>(tidx, cbase, tl, sid);

  // cast+transpose all weights to bf16 [N][K]
  tw_kernel<<<dim3(I_DIM / 64, H / 64, E), 256, 0, stream>>>(w_gate, wg_t, H, I_DIM);
  tw_kernel<<<dim3(I_DIM / 64, H / 64, E), 256, 0, stream>>>(w_up,   wu_t, H, I_DIM);
  tw_kernel<<<dim3(H / 64, I_DIM / 64, E), 256, 0, stream>>>(w_down, wd_t, I_DIM, H);
  tw_kernel<<<dim3(IS_DIM / 64, H / 64, 1), 256, 0, stream>>>(sw_gate, swg_t, H, IS_DIM);
  tw_kernel<<<dim3(IS_DIM / 64, H / 64, 1), 256, 0, stream>>>(sw_up,   swu_t, H, IS_DIM);
  tw_kernel<<<dim3(H / 64, IS_DIM / 64, 1), 256, 0, stream>>>(sw_down, swd_t, IS_DIM, H);

  // routed gate+up -> Sr  (reads wg_t/wu_t; must finish before Yr alias is written)
  gateup_kernel<<<dim3(I_DIM / 64, CAP / 128, E), 256, 0, stream>>>(
      xb, wg_t, wu_t, Sr, tl, cnt, I_DIM, (long long)H * I_DIM, (long long)CAP * I_DIM);
  // shared gate+up -> Ss
  gateup_kernel<<<dim3(IS_DIM / 64, T_TOK / 128, 1), 256, 0, stream>>>(
      xb, swg_t, swu_t, Ss, nullptr, nullptr, IS_DIM, 0, 0);
  // shared down: fp32 store, fully initializes out
  down_kernel<<<dim3(H / 128, T_TOK / 128, 1), 256, 0, stream>>>(
      Ss, swd_t, out, nullptr, nullptr, IS_DIM, 0, 0);
  // routed down: bf16 stores into slot buffer (Yr aliases wg_t region — safe now)
  down_kernel<<<dim3(H / 128, CAP / 128, E), 256, 0, stream>>>(
      Sr, wd_t, nullptr, Yr, cnt, I_DIM, (long long)I_DIM * H, (long long)CAP * I_DIM);
  // final combine
  combine_kernel<<<T_TOK, 256, 0, stream>>>(Yr, sid, twt, out);
}